// Round 6
// baseline (150.955 us; speedup 1.0000x reference)
//
#include <hip/hip_runtime.h>
#include <stdint.h>

typedef __attribute__((ext_vector_type(8))) short short8;
typedef __attribute__((ext_vector_type(4))) float f32x4;

static constexpr int D = 128;

static __device__ __forceinline__ unsigned short f32_to_bf16(float f) {
  unsigned int u = __builtin_bit_cast(unsigned int, f);
  return (unsigned short)((u + 0x7FFFu + ((u >> 16) & 1u)) >> 16);
}
static __device__ __forceinline__ float bf16_to_f32(unsigned short h) {
  return __builtin_bit_cast(float, ((unsigned int)h) << 16);
}

extern "C" __global__ __launch_bounds__(256) void k_zero(unsigned int* __restrict__ p, int n) {
  int i = blockIdx.x * 256 + threadIdx.x;
  if (i < n) p[i] = 0u;
}

// One wave per feature row: bf16 hi/lo split + fp32 row norm.
extern "C" __global__ __launch_bounds__(64) void k_prep_feat(
    const float* __restrict__ x, unsigned short* __restrict__ xh,
    unsigned short* __restrict__ xl, float* __restrict__ x2) {
  const int b = blockIdx.x, lane = threadIdx.x;
  const float2 f = *(const float2*)(x + (size_t)b * D + lane * 2);
  const unsigned short h0 = f32_to_bf16(f.x), h1 = f32_to_bf16(f.y);
  const unsigned short l0 = f32_to_bf16(f.x - bf16_to_f32(h0));
  const unsigned short l1 = f32_to_bf16(f.y - bf16_to_f32(h1));
  ((unsigned int*)xh)[(size_t)b * 64 + lane] = (unsigned int)h0 | ((unsigned int)h1 << 16);
  ((unsigned int*)xl)[(size_t)b * 64 + lane] = (unsigned int)l0 | ((unsigned int)l1 << 16);
  float s = fmaf(f.x, f.x, f.y * f.y);
  #pragma unroll
  for (int m = 1; m < 64; m <<= 1) s += __shfl_xor(s, m, 64);
  if (lane == 0) x2[b] = s;
}

// One wave per (padded) prototype row: hi/lo split, norm, padded label, class histogram.
extern "C" __global__ __launch_bounds__(64) void k_prep_proto(
    const float* __restrict__ pf, const int* __restrict__ plab_in,
    unsigned short* __restrict__ ph, unsigned short* __restrict__ pl,
    float* __restrict__ p2, int* __restrict__ plab, int* __restrict__ cc, int P) {
  const int r = blockIdx.x, lane = threadIdx.x;
  if (r < P) {
    const float2 f = *(const float2*)(pf + (size_t)r * D + lane * 2);
    const unsigned short h0 = f32_to_bf16(f.x), h1 = f32_to_bf16(f.y);
    const unsigned short l0 = f32_to_bf16(f.x - bf16_to_f32(h0));
    const unsigned short l1 = f32_to_bf16(f.y - bf16_to_f32(h1));
    ((unsigned int*)ph)[(size_t)r * 64 + lane] = (unsigned int)h0 | ((unsigned int)h1 << 16);
    ((unsigned int*)pl)[(size_t)r * 64 + lane] = (unsigned int)l0 | ((unsigned int)l1 << 16);
    float s = fmaf(f.x, f.x, f.y * f.y);
    #pragma unroll
    for (int m = 1; m < 64; m <<= 1) s += __shfl_xor(s, m, 64);
    if (lane == 0) {
      p2[r] = s;
      const int lb = plab_in[r];
      plab[r] = lb;
      atomicAdd(&cc[lb & 255], 1);
    }
  } else {
    // pad rows: zero features, huge norm -> dist ~1e15 -> exp = 0; label -1 never matches
    ((unsigned int*)ph)[(size_t)r * 64 + lane] = 0u;
    ((unsigned int*)pl)[(size_t)r * 64 + lane] = 0u;
    if (lane == 0) { p2[r] = 1e30f; plab[r] = -1; }
  }
}

// Main fused kernel: per block 4 waves x 32 feature rows (A-frags in regs),
// proto tiles of 32 rows staged to LDS (hi+lo, XOR-swizzled), 16x16x32 bf16 MFMA
// with 3-term hi/lo split, fused sqrt/exp epilogue, per-row atomics.
extern "C" __global__ __launch_bounds__(256, 3) void k_dce_main(
    const unsigned short* __restrict__ xh, const unsigned short* __restrict__ xl,
    const unsigned short* __restrict__ ph, const unsigned short* __restrict__ pl,
    const float* __restrict__ x2, const float* __restrict__ p2,
    const int* __restrict__ lab, const int* __restrict__ plab,
    float* __restrict__ sum_e, float* __restrict__ sum_d,
    int B, int NT) {
  __shared__ unsigned char lds[16384];  // [0..8191] hi tile, [8192..] lo tile

  const int tid = threadIdx.x;
  const int wid = tid >> 6;
  const int lane = tid & 63;
  const int l15 = lane & 15;
  const int lg = lane >> 4;

  const int rb = blockIdx.x * 128 + wid * 32;

  // A fragments: 2 rowsets x 4 K-chunks, hi and lo (row = lane&15, k = (lane>>4)*8+j)
  short8 ah[2][4], al[2][4];
  #pragma unroll
  for (int rs = 0; rs < 2; ++rs) {
    int row = rb + rs * 16 + l15; if (row >= B) row = B - 1;
    #pragma unroll
    for (int c = 0; c < 4; ++c) {
      const int k = c * 32 + lg * 8;
      ah[rs][c] = *(const short8*)(xh + (size_t)row * D + k);
      al[rs][c] = *(const short8*)(xl + (size_t)row * D + k);
    }
  }

  // per-lane output-row metadata (C layout: row = (lane>>4)*4 + reg)
  float x2v[2][4]; int labv[2][4];
  #pragma unroll
  for (int rs = 0; rs < 2; ++rs) {
    #pragma unroll
    for (int r = 0; r < 4; ++r) {
      int row = rb + rs * 16 + lg * 4 + r; if (row >= B) row = B - 1;
      x2v[rs][r] = x2[row];
      labv[rs][r] = lab[row];
    }
  }

  float acc_e[2][4] = {{0.f,0.f,0.f,0.f},{0.f,0.f,0.f,0.f}};
  float acc_d[2][4] = {{0.f,0.f,0.f,0.f},{0.f,0.f,0.f,0.f}};

  // staging geometry: 16 wave-loads of 1024B cover the 16KB (hi+lo) tile; 4 per wave.
  // LDS dest is linear (lane*16 appended by HW); source is pre-swizzled so that
  // reads at byte ^ ((row&7)<<4) return linear data (bank-conflict-free ds_read_b128).
  const unsigned char* srcb[4];
  unsigned char* dstb[4];
  #pragma unroll
  for (int q = 0; q < 4; ++q) {
    const int jj = wid * 4 + q;
    const int type = jj >> 3, ch = jj & 7;
    const int r = ch * 4 + lg;
    const int srcoff = r * 256 + ((l15 * 16) ^ ((r & 7) << 4));
    srcb[q] = (const unsigned char*)(type ? pl : ph) + srcoff;
    dstb[q] = &lds[type * 8192 + ch * 1024];
  }

  for (int tp = blockIdx.y; tp < NT; tp += gridDim.y) {
    const size_t toff = (size_t)tp * 8192;
    #pragma unroll
    for (int q = 0; q < 4; ++q) {
      __builtin_amdgcn_global_load_lds(
          (const __attribute__((address_space(1))) void*)(srcb[q] + toff),
          (__attribute__((address_space(3))) void*)dstb[q], 16, 0, 0);
    }
    __syncthreads();  // compiler drains vmcnt before barrier -> tile visible

    #pragma unroll
    for (int s = 0; s < 2; ++s) {
      f32x4 acc0 = {0.f,0.f,0.f,0.f}, acc1 = {0.f,0.f,0.f,0.f};
      const int pr = s * 16 + l15;        // proto row within tile (B-frag col)
      const int rowbyte = pr * 256;
      const int swz = (pr & 7) << 4;
      #pragma unroll
      for (int c = 0; c < 4; ++c) {
        const int off = rowbyte + ((c * 64 + lg * 16) ^ swz);
        const short8 bh = *(const short8*)&lds[off];
        const short8 bl = *(const short8*)&lds[8192 + off];
        acc0 = __builtin_amdgcn_mfma_f32_16x16x32_bf16(ah[0][c], bh, acc0, 0, 0, 0);
        acc1 = __builtin_amdgcn_mfma_f32_16x16x32_bf16(ah[1][c], bh, acc1, 0, 0, 0);
        acc0 = __builtin_amdgcn_mfma_f32_16x16x32_bf16(ah[0][c], bl, acc0, 0, 0, 0);
        acc1 = __builtin_amdgcn_mfma_f32_16x16x32_bf16(ah[1][c], bl, acc1, 0, 0, 0);
        acc0 = __builtin_amdgcn_mfma_f32_16x16x32_bf16(al[0][c], bh, acc0, 0, 0, 0);
        acc1 = __builtin_amdgcn_mfma_f32_16x16x32_bf16(al[1][c], bh, acc1, 0, 0, 0);
      }
      const int col = tp * 32 + s * 16 + l15;
      const float p2c = p2[col];
      const int plc = plab[col];
      #pragma unroll
      for (int rs = 0; rs < 2; ++rs) {
        const f32x4 a = rs ? acc1 : acc0;
        #pragma unroll
        for (int r = 0; r < 4; ++r) {
          const float S = a[r];
          const float d2 = fmaxf(x2v[rs][r] + p2c - 2.0f * S, 1e-12f);
          const float dist = sqrtf(d2);
          acc_e[rs][r] += __expf(-dist);                       // GAMMA = 1
          acc_d[rs][r] += (plc == labv[rs][r]) ? dist : 0.0f;  // masked dist sum
        }
      }
    }
    __syncthreads();  // done reading tile before next stage overwrites
  }

  // reduce over the 16 lanes sharing each output row, then one atomic per row
  #pragma unroll
  for (int rs = 0; rs < 2; ++rs) {
    #pragma unroll
    for (int r = 0; r < 4; ++r) {
      float e = acc_e[rs][r], d = acc_d[rs][r];
      #pragma unroll
      for (int m = 1; m < 16; m <<= 1) {
        e += __shfl_xor(e, m, 64);
        d += __shfl_xor(d, m, 64);
      }
      if (l15 == 0) {
        const int row = rb + rs * 16 + lg * 4 + r;
        if (row < B) {
          atomicAdd(&sum_e[row], e);
          atomicAdd(&sum_d[row], d);
        }
      }
    }
  }
}

extern "C" __global__ __launch_bounds__(256) void k_combine(
    const float* __restrict__ sum_e, const float* __restrict__ sum_d,
    const int* __restrict__ lab, const int* __restrict__ cc,
    float* __restrict__ out, int B) {
  const int b = blockIdx.x * 256 + threadIdx.x;
  if (b < B) {
    const float cnt = (float)cc[lab[b] & 255];
    out[b] = cnt * logf(sum_e[b]) + sum_d[b];
  }
}

extern "C" void kernel_launch(void* const* d_in, const int* in_sizes, int n_in,
                              void* d_out, int out_size, void* d_ws, size_t ws_size,
                              hipStream_t stream) {
  (void)n_in; (void)out_size; (void)ws_size;
  const float* feat = (const float*)d_in[0];
  const int* lab = (const int*)d_in[1];
  const float* pf = (const float*)d_in[2];
  const int* plab_in = (const int*)d_in[3];
  const int B = in_sizes[0] / D;        // 4096
  const int P = in_sizes[3];            // 10000
  const int P_pad = (P + 31) & ~31;     // 10016
  const int NT = P_pad / 32;            // 313

  uint8_t* ws = (uint8_t*)d_ws;
  size_t cur = 0;
  auto carve = [&](size_t bytes) {
    size_t off = cur;
    cur = (cur + bytes + 255) & ~(size_t)255;
    return off;
  };
  unsigned short* xh = (unsigned short*)(ws + carve((size_t)B * D * 2));
  unsigned short* xl = (unsigned short*)(ws + carve((size_t)B * D * 2));
  unsigned short* ph = (unsigned short*)(ws + carve((size_t)P_pad * D * 2));
  unsigned short* pl = (unsigned short*)(ws + carve((size_t)P_pad * D * 2));
  float* x2 = (float*)(ws + carve((size_t)B * 4));
  float* p2 = (float*)(ws + carve((size_t)P_pad * 4));
  int* plab = (int*)(ws + carve((size_t)P_pad * 4));
  // contiguous zero-init region: cc(256 ints) | sum_e(B f32) | sum_d(B f32)
  int* cc = (int*)(ws + carve(256 * 4 + (size_t)B * 4 * 2));
  float* sum_e = (float*)(cc + 256);
  float* sum_d = sum_e + B;
  float* out = (float*)d_out;

  const int zwords = 256 + 2 * B;
  k_zero<<<dim3((zwords + 255) / 256), dim3(256), 0, stream>>>((unsigned int*)cc, zwords);
  k_prep_feat<<<dim3(B), dim3(64), 0, stream>>>(feat, xh, xl, x2);
  k_prep_proto<<<dim3(P_pad), dim3(64), 0, stream>>>(pf, plab_in, ph, pl, p2, plab, cc, P);
  dim3 grid((B + 127) / 128, 24);  // 32 b-blocks x 24 P-chunks = 768 blocks
  k_dce_main<<<grid, dim3(256), 0, stream>>>(xh, xl, ph, pl, x2, p2, lab, plab,
                                             sum_e, sum_d, B, NT);
  k_combine<<<dim3((B + 255) / 256), dim3(256), 0, stream>>>(sum_e, sum_d, lab, cc, out, B);
}

// Round 7
// 140.614 us; speedup vs baseline: 1.0735x; 1.0735x over previous
//
#include <hip/hip_runtime.h>
#include <stdint.h>

typedef __attribute__((ext_vector_type(8))) short short8;
typedef __attribute__((ext_vector_type(4))) float f32x4;

static constexpr int D = 128;

static __device__ __forceinline__ unsigned short f32_to_bf16(float f) {
  unsigned int u = __builtin_bit_cast(unsigned int, f);
  return (unsigned short)((u + 0x7FFFu + ((u >> 16) & 1u)) >> 16);
}
static __device__ __forceinline__ float bf16_to_f32(unsigned short h) {
  return __builtin_bit_cast(float, ((unsigned int)h) << 16);
}

// Fused prep: feat hi/lo split + norms (blocks [0,NBF)), proto split + norms +
// padding (blocks [NBF,NBF+NBP)), sum_e/sum_d zeroing (spread over feat blocks),
// class histogram (last block, LDS-atomic, no global contention).
extern "C" __global__ __launch_bounds__(256) void k_prep(
    const float* __restrict__ x, const float* __restrict__ pf,
    const int* __restrict__ plab_in,
    unsigned short* __restrict__ xh, unsigned short* __restrict__ xl,
    unsigned short* __restrict__ ph, unsigned short* __restrict__ pl,
    float* __restrict__ x2, float* __restrict__ p2,
    int* __restrict__ plab, int* __restrict__ cc,
    unsigned int* __restrict__ zero32,
    int B, int P, int NBF, int NBP) {
  __shared__ int hist[256];
  const int bid = blockIdx.x;
  const int tid = threadIdx.x;
  const int wid = tid >> 6, lane = tid & 63;

  if (bid < NBF) {
    const int b = bid * 4 + wid;                 // NBF*4 == B exactly
    const float2 f = *(const float2*)(x + (size_t)b * D + lane * 2);
    const unsigned short h0 = f32_to_bf16(f.x), h1 = f32_to_bf16(f.y);
    const unsigned short l0 = f32_to_bf16(f.x - bf16_to_f32(h0));
    const unsigned short l1 = f32_to_bf16(f.y - bf16_to_f32(h1));
    ((unsigned int*)xh)[(size_t)b * 64 + lane] = (unsigned int)h0 | ((unsigned int)h1 << 16);
    ((unsigned int*)xl)[(size_t)b * 64 + lane] = (unsigned int)l0 | ((unsigned int)l1 << 16);
    float s = fmaf(f.x, f.x, f.y * f.y);
    #pragma unroll
    for (int m = 1; m < 64; m <<= 1) s += __shfl_xor(s, m, 64);
    if (lane == 0) x2[b] = s;
    if (tid < 8) zero32[bid * 8 + tid] = 0u;     // NBF*8 == 2*B words
  } else if (bid < NBF + NBP) {
    const int r = (bid - NBF) * 4 + wid;         // NBP*4 == P_pad
    if (r < P) {
      const float2 f = *(const float2*)(pf + (size_t)r * D + lane * 2);
      const unsigned short h0 = f32_to_bf16(f.x), h1 = f32_to_bf16(f.y);
      const unsigned short l0 = f32_to_bf16(f.x - bf16_to_f32(h0));
      const unsigned short l1 = f32_to_bf16(f.y - bf16_to_f32(h1));
      ((unsigned int*)ph)[(size_t)r * 64 + lane] = (unsigned int)h0 | ((unsigned int)h1 << 16);
      ((unsigned int*)pl)[(size_t)r * 64 + lane] = (unsigned int)l0 | ((unsigned int)l1 << 16);
      float s = fmaf(f.x, f.x, f.y * f.y);
      #pragma unroll
      for (int m = 1; m < 64; m <<= 1) s += __shfl_xor(s, m, 64);
      if (lane == 0) { p2[r] = s; plab[r] = plab_in[r]; }
    } else {
      // pad rows: zero features, huge norm -> exp underflows to 0; label -1 never matches
      ((unsigned int*)ph)[(size_t)r * 64 + lane] = 0u;
      ((unsigned int*)pl)[(size_t)r * 64 + lane] = 0u;
      if (lane == 0) { p2[r] = 1e30f; plab[r] = -1; }
    }
  } else {
    // histogram block: one block, LDS atomics only
    hist[tid] = 0;
    __syncthreads();
    for (int r = tid; r < P; r += 256) atomicAdd(&hist[plab_in[r] & 255], 1);
    __syncthreads();
    cc[tid] = hist[tid];
  }
}

// Main fused kernel: per block 4 waves x 32 feature rows (A-frags in regs),
// proto tiles of 32 rows staged to LDS (hi+lo, XOR-swizzled source so linear
// global_load_lds dest + XOR'd ds_read_b128 return linear data), DOUBLE-BUFFERED:
// issue next tile's global_load_lds before computing current tile; the single
// trailing __syncthreads (vmcnt(0)+barrier) lands after ~1300cy of compute cover.
extern "C" __global__ __launch_bounds__(256, 4) void k_dce_main(
    const unsigned short* __restrict__ xh, const unsigned short* __restrict__ xl,
    const unsigned short* __restrict__ ph, const unsigned short* __restrict__ pl,
    const float* __restrict__ x2, const float* __restrict__ p2,
    const int* __restrict__ lab, const int* __restrict__ plab,
    float* __restrict__ sum_e, float* __restrict__ sum_d,
    int B, int NT) {
  __shared__ unsigned char lds[32768];  // 2 buffers x (8KB hi + 8KB lo)

  const int tid = threadIdx.x;
  const int wid = tid >> 6;
  const int lane = tid & 63;
  const int l15 = lane & 15;
  const int lg = lane >> 4;

  const int rb = blockIdx.x * 128 + wid * 32;

  // A fragments: 2 rowsets x 4 K-chunks, hi and lo (row = lane&15, k = (lane>>4)*8+j)
  short8 ah[2][4], al[2][4];
  #pragma unroll
  for (int rs = 0; rs < 2; ++rs) {
    int row = rb + rs * 16 + l15; if (row >= B) row = B - 1;
    #pragma unroll
    for (int c = 0; c < 4; ++c) {
      const int k = c * 32 + lg * 8;
      ah[rs][c] = *(const short8*)(xh + (size_t)row * D + k);
      al[rs][c] = *(const short8*)(xl + (size_t)row * D + k);
    }
  }

  // per-lane output-row metadata (C layout: row = (lane>>4)*4 + reg)
  float x2v[2][4]; int labv[2][4];
  #pragma unroll
  for (int rs = 0; rs < 2; ++rs) {
    #pragma unroll
    for (int r = 0; r < 4; ++r) {
      int row = rb + rs * 16 + lg * 4 + r; if (row >= B) row = B - 1;
      x2v[rs][r] = x2[row];
      labv[rs][r] = lab[row];
    }
  }

  float acc_e[2][4] = {{0.f,0.f,0.f,0.f},{0.f,0.f,0.f,0.f}};
  float acc_d[2][4] = {{0.f,0.f,0.f,0.f},{0.f,0.f,0.f,0.f}};

  // staging geometry: 16 wave-loads of 1024B cover one 16KB (hi+lo) tile; 4/wave.
  const unsigned char* srcb[4];
  int dstoff[4];
  #pragma unroll
  for (int q = 0; q < 4; ++q) {
    const int jj = wid * 4 + q;
    const int type = jj >> 3, ch = jj & 7;
    const int r = ch * 4 + lg;
    const int srcoff = r * 256 + ((l15 * 16) ^ ((r & 7) << 4));
    srcb[q] = (const unsigned char*)(type ? pl : ph) + srcoff;
    dstoff[q] = type * 8192 + ch * 1024;
  }

  auto stage = [&](int cbuf, int t) {
    const size_t toff = (size_t)t * 8192;
    const int base = cbuf * 16384;
    #pragma unroll
    for (int q = 0; q < 4; ++q) {
      __builtin_amdgcn_global_load_lds(
          (const __attribute__((address_space(1))) void*)(srcb[q] + toff),
          (__attribute__((address_space(3))) void*)(&lds[base + dstoff[q]]), 16, 0, 0);
    }
  };

  // prologue: stage first tile, drain, then pipeline
  stage(0, blockIdx.y);
  __syncthreads();

  int cur = 0;
  for (int tp = blockIdx.y; tp < NT; tp += gridDim.y) {
    const int tn = tp + gridDim.y;
    if (tn < NT) stage(cur ^ 1, tn);   // prefetch next tile into other buffer

    const int lbase = cur * 16384;
    #pragma unroll
    for (int s = 0; s < 2; ++s) {
      f32x4 acc0 = {0.f,0.f,0.f,0.f}, acc1 = {0.f,0.f,0.f,0.f};
      const int pr = s * 16 + l15;        // proto row within tile (B-frag col)
      const int rowbyte = pr * 256;
      const int swz = (pr & 7) << 4;
      #pragma unroll
      for (int c = 0; c < 4; ++c) {
        const int off = lbase + rowbyte + ((c * 64 + lg * 16) ^ swz);
        const short8 bh = *(const short8*)&lds[off];
        const short8 bl = *(const short8*)&lds[8192 + off];
        acc0 = __builtin_amdgcn_mfma_f32_16x16x32_bf16(ah[0][c], bh, acc0, 0, 0, 0);
        acc1 = __builtin_amdgcn_mfma_f32_16x16x32_bf16(ah[1][c], bh, acc1, 0, 0, 0);
        acc0 = __builtin_amdgcn_mfma_f32_16x16x32_bf16(ah[0][c], bl, acc0, 0, 0, 0);
        acc1 = __builtin_amdgcn_mfma_f32_16x16x32_bf16(ah[1][c], bl, acc1, 0, 0, 0);
        acc0 = __builtin_amdgcn_mfma_f32_16x16x32_bf16(al[0][c], bh, acc0, 0, 0, 0);
        acc1 = __builtin_amdgcn_mfma_f32_16x16x32_bf16(al[1][c], bh, acc1, 0, 0, 0);
      }
      const int col = tp * 32 + s * 16 + l15;
      const float p2c = p2[col];
      const int plc = plab[col];
      #pragma unroll
      for (int rs = 0; rs < 2; ++rs) {
        const f32x4 a = rs ? acc1 : acc0;
        #pragma unroll
        for (int r = 0; r < 4; ++r) {
          const float S = a[r];
          const float d2 = fmaxf(x2v[rs][r] + p2c - 2.0f * S, 1e-12f);
          const float dist = __builtin_amdgcn_sqrtf(d2);  // raw v_sqrt_f32, ~1ulp
          acc_e[rs][r] += __expf(-dist);                       // GAMMA = 1
          acc_d[rs][r] += (plc == labv[rs][r]) ? dist : 0.0f;  // masked dist sum
        }
      }
    }
    // single barrier per tile: drains prefetch (issued ~1300cy ago -> cheap) AND
    // guarantees all waves done reading lds[cur] before it is overwritten next iter
    __syncthreads();
    cur ^= 1;
  }

  // reduce over the 16 lanes sharing each output row, then one atomic per row
  #pragma unroll
  for (int rs = 0; rs < 2; ++rs) {
    #pragma unroll
    for (int r = 0; r < 4; ++r) {
      float e = acc_e[rs][r], d = acc_d[rs][r];
      #pragma unroll
      for (int m = 1; m < 16; m <<= 1) {
        e += __shfl_xor(e, m, 64);
        d += __shfl_xor(d, m, 64);
      }
      if (l15 == 0) {
        const int row = rb + rs * 16 + lg * 4 + r;
        if (row < B) {
          atomicAdd(&sum_e[row], e);
          atomicAdd(&sum_d[row], d);
        }
      }
    }
  }
}

extern "C" __global__ __launch_bounds__(256) void k_combine(
    const float* __restrict__ sum_e, const float* __restrict__ sum_d,
    const int* __restrict__ lab, const int* __restrict__ cc,
    float* __restrict__ out, int B) {
  const int b = blockIdx.x * 256 + threadIdx.x;
  if (b < B) {
    const float cnt = (float)cc[lab[b] & 255];
    out[b] = cnt * logf(sum_e[b]) + sum_d[b];
  }
}

extern "C" void kernel_launch(void* const* d_in, const int* in_sizes, int n_in,
                              void* d_out, int out_size, void* d_ws, size_t ws_size,
                              hipStream_t stream) {
  (void)n_in; (void)out_size; (void)ws_size;
  const float* feat = (const float*)d_in[0];
  const int* lab = (const int*)d_in[1];
  const float* pf = (const float*)d_in[2];
  const int* plab_in = (const int*)d_in[3];
  const int B = in_sizes[0] / D;        // 4096
  const int P = in_sizes[3];            // 10000
  const int P_pad = (P + 31) & ~31;     // 10016
  const int NT = P_pad / 32;            // 313

  uint8_t* ws = (uint8_t*)d_ws;
  size_t cur = 0;
  auto carve = [&](size_t bytes) {
    size_t off = cur;
    cur = (cur + bytes + 255) & ~(size_t)255;
    return off;
  };
  unsigned short* xh = (unsigned short*)(ws + carve((size_t)B * D * 2));
  unsigned short* xl = (unsigned short*)(ws + carve((size_t)B * D * 2));
  unsigned short* ph = (unsigned short*)(ws + carve((size_t)P_pad * D * 2));
  unsigned short* pl = (unsigned short*)(ws + carve((size_t)P_pad * D * 2));
  float* x2 = (float*)(ws + carve((size_t)B * 4));
  float* p2 = (float*)(ws + carve((size_t)P_pad * 4));
  int* plab = (int*)(ws + carve((size_t)P_pad * 4));
  // region: cc(256 ints, fully written by hist block) | sum_e(B f32) | sum_d(B f32)
  int* cc = (int*)(ws + carve(256 * 4 + (size_t)B * 4 * 2));
  float* sum_e = (float*)(cc + 256);
  float* sum_d = sum_e + B;
  float* out = (float*)d_out;

  const int NBF = B / 4;        // 1024 (B=4096 is a multiple of 4)
  const int NBP = P_pad / 4;    // 2504
  k_prep<<<dim3(NBF + NBP + 1), dim3(256), 0, stream>>>(
      feat, pf, plab_in, xh, xl, ph, pl, x2, p2, plab, cc,
      (unsigned int*)sum_e, B, P, NBF, NBP);
  dim3 grid(B / 128, 32);       // 32 x 32 = 1024 blocks = 4/CU
  k_dce_main<<<grid, dim3(256), 0, stream>>>(xh, xl, ph, pl, x2, p2, lab, plab,
                                             sum_e, sum_d, B, NT);
  k_combine<<<dim3((B + 255) / 256), dim3(256), 0, stream>>>(sum_e, sum_d, lab, cc, out, B);
}